// Round 17
// baseline (129.720 us; speedup 1.0000x reference)
//
#include <hip/hip_runtime.h>

typedef __attribute__((ext_vector_type(8))) short bfrag;
typedef __attribute__((ext_vector_type(4))) float ffrag;
typedef __attribute__((ext_vector_type(8))) unsigned short us8;
typedef __attribute__((ext_vector_type(4))) unsigned short us4;
typedef __attribute__((ext_vector_type(2))) unsigned short us2;

#define DEVI static __device__ __forceinline__

DEVI unsigned short f2bf(float f){
  unsigned int u = __float_as_uint(f);
  u += 0x7fffu + ((u >> 16) & 1u);   // round-to-nearest-even
  return (unsigned short)(u >> 16);
}
DEVI float fexp2(float x){ float r; asm("v_exp_f32 %0, %1" : "=v"(r) : "v"(x)); return r; }
DEVI unsigned int cvt_pk_bf16(float lo, float hi){
  unsigned int r;
  asm("v_cvt_pk_bf16_f32 %0, %1, %2" : "=v"(r) : "v"(lo), "v"(hi));
  return r;
}
// XOR swizzle in ushort units: granule = 8 bf16 (16B). Row-major tile,
// row stride 64 / 256 ushorts. Bijective per row; consistent write+read.
DEVI int swz64(int r, int c){ return ((r << 6) + c) ^ ((r & 7) << 3); }
DEVI int swz256(int r, int c){ return ((r << 8) + c) ^ ((r & 7) << 3); }

// global->LDS DMA, 16B per lane. LDS dest = wave-uniform base + lane*16
// (linear); the swizzle lives in the per-lane GLOBAL source granule.
DEVI void gload16(const unsigned short* g, unsigned short* l){
  __builtin_amdgcn_global_load_lds(
      (const __attribute__((address_space(1))) unsigned int*)g,
      (__attribute__((address_space(3))) unsigned int*)l, 16, 0, 0);
}

// -- 0) fused: GroupNorm stats+normalize+transpose (blocks 0..127) and
//       W->bf16 prep (blocks 128..383).
__global__ __launch_bounds__(256) void prep_gn(
    const float* __restrict__ x, const float* __restrict__ gw,
    const float* __restrict__ gb, const float* __restrict__ qkvw,
    const float* __restrict__ qkvb, const float* __restrict__ pw,
    unsigned short* __restrict__ wq, unsigned short* __restrict__ wp,
    float* __restrict__ bq, unsigned short* __restrict__ xnt){
  __shared__ float ps[4], pq[4];
  if (blockIdx.x >= 128){
    const int i = (blockIdx.x - 128) * 256 + threadIdx.x;  // i < 65536
    const float qs = 0.125f * 1.44269504f;                 // hd^-0.5 * log2(e)
    if (i < 49152){                                        // qkv_w
      float4 v = ((const float4*)qkvw)[i];
      float sc = (i < 16384) ? qs : 1.f;
      us4 u; u[0]=f2bf(v.x*sc); u[1]=f2bf(v.y*sc); u[2]=f2bf(v.z*sc); u[3]=f2bf(v.w*sc);
      ((us4*)wq)[i] = u;
    }
    if (i < 16384){                                        // proj_w
      float4 v = ((const float4*)pw)[i];
      us4 u; u[0]=f2bf(v.x); u[1]=f2bf(v.y); u[2]=f2bf(v.z); u[3]=f2bf(v.w);
      ((us4*)wp)[i] = u;
    }
    if (i < 768) bq[i] = qkvb[i] * (i < 256 ? qs : 1.f);
    return;
  }
  const int b = blockIdx.x >> 5, g = blockIdx.x & 31;
  const int t = threadIdx.x;
  const float* xb = x + (((size_t)b * 256 + g * 8) << 12);
  float s = 0.f, q = 0.f;
  #pragma unroll
  for (int c = 0; c < 8; ++c){
    const float4* base = (const float4*)(xb + ((size_t)c << 12));
    #pragma unroll
    for (int e = 0; e < 4; ++e){
      float4 v = base[e * 256 + t];
      s += v.x + v.y + v.z + v.w;
      q += v.x * v.x + v.y * v.y + v.z * v.z + v.w * v.w;
    }
  }
  #pragma unroll
  for (int m = 32; m; m >>= 1){ s += __shfl_down(s, m); q += __shfl_down(q, m); }
  if ((t & 63) == 0){ ps[t >> 6] = s; pq[t >> 6] = q; }
  __syncthreads();
  float S = ps[0] + ps[1] + ps[2] + ps[3];
  float Q = pq[0] + pq[1] + pq[2] + pq[3];
  float mean = S * (1.f / 32768.f);
  float var  = Q * (1.f / 32768.f) - mean * mean;
  float rstd = rsqrtf(var + 1e-5f);
  float sc[8], sh[8];
  #pragma unroll
  for (int c = 0; c < 8; ++c){
    sc[c] = gw[g * 8 + c] * rstd;
    sh[c] = gb[g * 8 + c] - mean * sc[c];
  }
  unsigned short* dst = xnt + (((size_t)b << 12) << 8) + (g << 3);
  #pragma unroll
  for (int e = 0; e < 16; ++e){
    const int n = e * 256 + t;
    us8 u;
    #pragma unroll
    for (int c = 0; c < 8; ++c)
      u[c] = f2bf(xb[((size_t)c << 12) + n] * sc[c] + sh[c]);
    *(us8*)(dst + ((size_t)n << 8)) = u;
  }
}

// ---- 3) QKV GEMM: qkv[o][n] = W[o][c] @ xn[c][n] + b; writes q_t,k_t,v ----
__global__ __launch_bounds__(256) void qkv_gemm(
    const unsigned short* __restrict__ xnt, const unsigned short* __restrict__ W,
    const float* __restrict__ bias, unsigned short* __restrict__ qt,
    unsigned short* __restrict__ kt, unsigned short* __restrict__ vt){
  const int n0 = blockIdx.x << 6, MT = blockIdx.y, b = blockIdx.z;
  const int t = threadIdx.x, l = t & 63, w = t >> 6;
  __shared__ __align__(16) unsigned short AB[32768];   // A: [0..16383], B: [16384..]
  unsigned short* Al = AB;
  unsigned short* Bl = AB + 16384;
  const unsigned short* Asrc = W + (size_t)(MT << 6) * 256;
  const unsigned short* Bsrc = xnt + ((((size_t)b << 12) + n0) << 8);
  #pragma unroll
  for (int e = 0; e < 8; ++e){
    const int idx = e * 256 + t;                 // granule index 0..2047
    const int r = idx >> 5, g = idx & 31;
    const int gs = (g ^ (r & 7)) << 3;           // swizzled source granule
    unsigned short* db = &AB[(e * 256 + (w << 6)) << 3];   // wave-uniform
    gload16(Asrc + (r << 8) + gs, db);
    gload16(Bsrc + (r << 8) + gs, db + 16384);
  }
  __syncthreads();
  ffrag acc[4] = {{0,0,0,0},{0,0,0,0},{0,0,0,0},{0,0,0,0}};
  #pragma unroll
  for (int kc = 0; kc < 8; ++kc){
    bfrag a = *(const bfrag*)&Al[swz256((w << 4) + (l & 15), (kc << 5) + ((l >> 4) << 3))];
    #pragma unroll
    for (int fc = 0; fc < 4; ++fc){
      bfrag bb = *(const bfrag*)&Bl[swz256((fc << 4) + (l & 15), (kc << 5) + ((l >> 4) << 3))];
      acc[fc] = __builtin_amdgcn_mfma_f32_16x16x32_bf16(a, bb, acc[fc], 0, 0, 0);
    }
  }
  const int which = MT >> 2, h = MT & 3;
  const int d0 = (w << 4) + ((l >> 4) << 2);
  float bi[4];
  #pragma unroll
  for (int r = 0; r < 4; ++r) bi[r] = bias[(MT << 6) + d0 + r];
  #pragma unroll
  for (int fc = 0; fc < 4; ++fc){
    int n = n0 + (fc << 4) + (l & 15);
    if (which < 2){                 // q,k -> [b][h][n][d]
      unsigned short* dst = (which == 0 ? qt : kt) +
          (((size_t)(b * 4 + h)) << 18) + ((size_t)n << 6) + d0;
      us4 u;
      #pragma unroll
      for (int r = 0; r < 4; ++r) u[r] = f2bf(acc[fc][r] + bi[r]);
      *(us4*)dst = u;
    } else {                        // v -> [b][h][d][n], k-permuted cols
      const int np = n0 + ((fc & 2) << 4) + (((l >> 2) & 3) << 3)
                        + ((fc & 1) << 2) + (l & 3);
      #pragma unroll
      for (int r = 0; r < 4; ++r)
        vt[((((size_t)(b * 4 + h)) << 6) + d0 + r) * 4096 + np] = f2bf(acc[fc][r] + bi[r]);
    }
  }
}

// --- 4) flash attention, 8 waves / 512 thr, q-tile 64, in-block split-K ---
// TLP round: 32 KB LDS (2-buffer K/V), grid 1024 -> 4 blocks/CU target.
// Independent co-resident blocks de-phase: one block's QK-MFMA overlaps
// another's exp2-VALU (no shared barriers). Body = r16's proven set:
// no max-tracking, rowsum-MFMA, cvt_pk pack, setprio, DMA w/ source swizzle,
// XCD-grouped decode (2 bh per XCD, K/V L2-hot).
__global__ __launch_bounds__(512, 6) void attn_kernel(
    const unsigned short* __restrict__ qt, const unsigned short* __restrict__ kt,
    const unsigned short* __restrict__ vt, unsigned short* __restrict__ at){
  const int id = blockIdx.x;                 // 0..1023
  const int xc = id & 7, k2 = id >> 3;       // XCD c gets 2 bh
  const int bhid = (xc << 1) + (k2 >> 6);
  const int qx = k2 & 63;
  const int b = bhid >> 2, h = bhid & 3;
  const int q0 = qx << 6;
  const int t = threadIdx.x, l = t & 63, w = t >> 6;   // w in 0..7
  const int wq = w & 3, kh = w >> 2;
  const size_t bh = (size_t)bhid;
  // kbuf0 @0, kbuf1 @4096, vbuf0 @8192, vbuf1 @12288 (ushort offsets). 32 KB.
  // Q staged in kbuf1 pre-loop.
  __shared__ __align__(16) unsigned short S[16384];
  const unsigned short* kbase = kt + (bh << 18);
  const unsigned short* vbase = vt + (bh << 18);

  const int row = t >> 3;                        // 0..63
  const int gx = ((t & 7) ^ (row & 7)) << 3;     // swizzled source granule col
  const int koff = (row << 6) + gx;
  unsigned short* ldst = &S[w << 9];             // wave-uniform dest base
  // prologue: Q -> kbuf1, K0 -> kbuf0, V0 -> vbuf0
  const unsigned short* qsrc = qt + (bh << 18) + ((size_t)q0 << 6);
  gload16(qsrc + koff, ldst + 4096);
  gload16(kbase + koff, ldst);
  gload16(vbase + (row << 12) + gx, ldst + 8192);
  asm volatile("s_waitcnt vmcnt(2)" ::: "memory");  // Q landed
  __builtin_amdgcn_s_barrier();
  __builtin_amdgcn_sched_barrier(0);
  // Q as B-operand: lane holds Q[q = q0 + wq*16 + (l&15)][d = (l>>4)*8 + j]
  bfrag bq0 = *(const bfrag*)&S[4096 + swz64((wq << 4) + (l & 15), (l >> 4) << 3)];
  bfrag bq1 = *(const bfrag*)&S[4096 + swz64((wq << 4) + (l & 15), 32 + ((l >> 4) << 3))];
  asm volatile("s_waitcnt lgkmcnt(0)" ::: "memory");
  __builtin_amdgcn_s_barrier();      // Q consumed; kbuf1 writable
  __builtin_amdgcn_sched_barrier(0);
  // issue tile 1 into kbuf1/vbuf1; wait K0,V0 landed
  gload16(kbase + 4096 + koff, ldst + 4096);
  gload16(vbase + (row << 12) + 64 + gx, ldst + 12288);
  asm volatile("s_waitcnt vmcnt(2)" ::: "memory");
  __builtin_amdgcn_s_barrier();
  __builtin_amdgcn_sched_barrier(0);

  ffrag acc[4] = {{0,0,0,0},{0,0,0,0},{0,0,0,0},{0,0,0,0}};
  ffrag zs = {0,0,0,0};                    // rowsum accumulator (row-indexed)
  const ffrag zf = {0.f, 0.f, 0.f, 0.f};
  bfrag onesB;
  #pragma unroll
  for (int j = 0; j < 8; ++j) onesB[j] = (short)0x3F80;   // bf16 1.0

  // one iteration body; kbr/vbr compile-time after inlining
  auto body = [&](int kbr, int vbr) __attribute__((always_inline)) {
    ffrag s[2];
    __builtin_amdgcn_s_setprio(1);
    #pragma unroll
    for (int j = 0; j < 2; ++j){
      const int fc = (kh << 1) + j;
      bfrag ak0 = *(const bfrag*)&S[kbr + swz64((fc << 4) + (l & 15), (l >> 4) << 3)];
      bfrag ak1 = *(const bfrag*)&S[kbr + swz64((fc << 4) + (l & 15), 32 + ((l >> 4) << 3))];
      ffrag z = __builtin_amdgcn_mfma_f32_16x16x32_bf16(ak0, bq0, zf, 0, 0, 0);
      z = __builtin_amdgcn_mfma_f32_16x16x32_bf16(ak1, bq1, z, 0, 0, 0);
      s[j] = z;
    }
    __builtin_amdgcn_s_setprio(0);
    float p[2][4];
    #pragma unroll
    for (int j = 0; j < 2; ++j){
      #pragma unroll
      for (int r = 0; r < 4; ++r) p[j][r] = fexp2(s[j][r]);
    }
    union { bfrag bb; unsigned int u[4]; } A;
    A.u[0] = cvt_pk_bf16(p[0][0], p[0][1]); A.u[1] = cvt_pk_bf16(p[0][2], p[0][3]);
    A.u[2] = cvt_pk_bf16(p[1][0], p[1][1]); A.u[3] = cvt_pk_bf16(p[1][2], p[1][3]);
    __builtin_amdgcn_s_setprio(1);
    zs = __builtin_amdgcn_mfma_f32_16x16x32_bf16(A.bb, onesB, zs, 0, 0, 0);
    #pragma unroll
    for (int fc = 0; fc < 4; ++fc){
      bfrag vv = *(const bfrag*)&S[vbr + swz64((fc << 4) + (l & 15),
                                              (kh << 5) + ((l >> 4) << 3))];
      acc[fc] = __builtin_amdgcn_mfma_f32_16x16x32_bf16(A.bb, vv, acc[fc], 0, 0, 0);
    }
    __builtin_amdgcn_s_setprio(0);
  };
  auto issue2 = [&](int kti2, int buf) __attribute__((always_inline)) {
    gload16(kbase + (kti2 << 12) + koff, ldst + (buf << 12));
    gload16(vbase + (row << 12) + (kti2 << 6) + gx, ldst + 8192 + (buf << 12));
  };

  // iter 0 (tile 1 already in flight)
  body(0, 8192);
  asm volatile("s_waitcnt vmcnt(0)" ::: "memory");
  __builtin_amdgcn_s_barrier();
  __builtin_amdgcn_sched_barrier(0);
  // iters 1..62 in pairs; iter e reads buf e&1, issues tile e+1 into (e+1)&1
  for (int e = 1; e < 63; e += 2){
    issue2(e + 1, 0);
    body(1 << 12, 8192 + (1 << 12));
    asm volatile("s_waitcnt vmcnt(0)" ::: "memory");
    __builtin_amdgcn_s_barrier();
    __builtin_amdgcn_sched_barrier(0);
    if (e + 2 < 64) issue2(e + 2, 1);
    body(0, 8192);
    asm volatile("s_waitcnt vmcnt(0)" ::: "memory");
    __builtin_amdgcn_s_barrier();
    __builtin_amdgcn_sched_barrier(0);
  }
  // iter 63: tile 63 landed (vmcnt(0) above); reads buf 1
  body(1 << 12, 8192 + (1 << 12));

  __syncthreads();                 // retire all tile reads; LDS free
  float* Sf = (float*)S;
  // phase 1: kh=1 publishes rowsums (row-indexed q = wq*16 + (l>>4)*4 + r)
  if (kh == 1 && (l & 15) == 0){
    #pragma unroll
    for (int r = 0; r < 4; ++r)
      Sf[4096 + (wq << 4) + ((l >> 4) << 2) + r] = zs[r];
  }
  __syncthreads();
  float inv[4];
  if (kh == 0){
    #pragma unroll
    for (int r = 0; r < 4; ++r)
      inv[r] = 1.f / (zs[r] + Sf[4096 + (wq << 4) + ((l >> 4) << 2) + r]);
  }
  __syncthreads();
  // phase 2: kh=1 publishes acc f32 (64q x 64d = 16 KB at Sf[0..4095])
  if (kh == 1){
    #pragma unroll
    for (int fc = 0; fc < 4; ++fc){
      #pragma unroll
      for (int r = 0; r < 4; ++r)
        Sf[((wq << 4) + ((l >> 4) << 2) + r) * 64 + (fc << 4) + (l & 15)] =
            acc[fc][r];
    }
  }
  __syncthreads();
  if (kh == 0){
    #pragma unroll
    for (int fc = 0; fc < 4; ++fc){
      #pragma unroll
      for (int r = 0; r < 4; ++r){
        const int ql = (wq << 4) + ((l >> 4) << 2) + r;
        float ob = Sf[ql * 64 + (fc << 4) + (l & 15)];
        float v = (acc[fc][r] + ob) * inv[r];
        at[((((size_t)b << 12) + q0 + ql) << 8) + (h << 6) + (fc << 4) + (l & 15)] =
            f2bf(v);
      }
    }
  }
}

// -------- 5) proj GEMM + bias + residual: out = x + W@attn_out + b --------
__global__ __launch_bounds__(256) void proj_gemm(
    const unsigned short* __restrict__ at, const unsigned short* __restrict__ W,
    const float* __restrict__ bias, const float* __restrict__ x,
    float* __restrict__ out){
  const int n0 = blockIdx.x << 6, MT = blockIdx.y, b = blockIdx.z;
  const int t = threadIdx.x, l = t & 63, w = t >> 6;
  __shared__ __align__(16) unsigned short AB[32768];   // A: [0..16383], B: [16384..]
  unsigned short* Al = AB;
  unsigned short* Bl = AB + 16384;
  const unsigned short* Asrc = W + (size_t)(MT << 6) * 256;
  const unsigned short* Bsrc = at + ((((size_t)b << 12) + n0) << 8);
  #pragma unroll
  for (int e = 0; e < 8; ++e){
    const int idx = e * 256 + t;
    const int r = idx >> 5, g = idx & 31;
    const int gs = (g ^ (r & 7)) << 3;
    unsigned short* db = &AB[(e * 256 + (w << 6)) << 3];
    gload16(Asrc + (r << 8) + gs, db);
    gload16(Bsrc + (r << 8) + gs, db + 16384);
  }
  __syncthreads();
  ffrag acc[4] = {{0,0,0,0},{0,0,0,0},{0,0,0,0},{0,0,0,0}};
  #pragma unroll
  for (int kc = 0; kc < 8; ++kc){
    bfrag a = *(const bfrag*)&Al[swz256((w << 4) + (l & 15), (kc << 5) + ((l >> 4) << 3))];
    #pragma unroll
    for (int fc = 0; fc < 4; ++fc){
      bfrag bb = *(const bfrag*)&Bl[swz256((fc << 4) + (l & 15), (kc << 5) + ((l >> 4) << 3))];
      acc[fc] = __builtin_amdgcn_mfma_f32_16x16x32_bf16(a, bb, acc[fc], 0, 0, 0);
    }
  }
  const int co = (MT << 6) + (w << 4) + ((l >> 4) << 2);
  #pragma unroll
  for (int fc = 0; fc < 4; ++fc){
    int n = n0 + (fc << 4) + (l & 15);
    #pragma unroll
    for (int r = 0; r < 4; ++r){
      size_t o = (((size_t)b * 256 + co + r) << 12) + n;
      out[o] = acc[fc][r] + bias[co + r] + x[o];
    }
  }
}

extern "C" void kernel_launch(void* const* d_in, const int* in_sizes, int n_in,
                              void* d_out, int out_size, void* d_ws, size_t ws_size,
                              hipStream_t stream){
  const float* x    = (const float*)d_in[0];
  const float* gw   = (const float*)d_in[1];
  const float* gb   = (const float*)d_in[2];
  const float* qkvw = (const float*)d_in[3];
  const float* qkvb = (const float*)d_in[4];
  const float* pw   = (const float*)d_in[5];
  const float* pb   = (const float*)d_in[6];
  float* out = (float*)d_out;

  unsigned short* xnt = (unsigned short*)((char*)d_ws + 16384);
  unsigned short* qt  = xnt + (size_t)4 * 4096 * 256;
  unsigned short* kt  = qt  + (size_t)16 * 4096 * 64;
  unsigned short* vt  = kt  + (size_t)16 * 4096 * 64;
  unsigned short* at  = vt  + (size_t)16 * 4096 * 64;
  unsigned short* wq  = at  + (size_t)4 * 4096 * 256;
  unsigned short* wp  = wq  + (size_t)768 * 256;
  float*          bq  = (float*)(wp + (size_t)256 * 256);

  prep_gn    <<<384, 256, 0, stream>>>(x, gw, gb, qkvw, qkvb, pw, wq, wp, bq, xnt);
  qkv_gemm   <<<dim3(64, 12, 4), 256, 0, stream>>>(xnt, wq, bq, qt, kt, vt);
  attn_kernel<<<dim3(1024), 512, 0, stream>>>(qt, kt, vt, at);
  proj_gemm  <<<dim3(64, 4, 4), 256, 0, stream>>>(at, wp, pb, x, out);
}

// Round 18
// 106.648 us; speedup vs baseline: 1.2163x; 1.2163x over previous
//
#include <hip/hip_runtime.h>

typedef __attribute__((ext_vector_type(8))) short bfrag;
typedef __attribute__((ext_vector_type(4))) float ffrag;
typedef __attribute__((ext_vector_type(8))) unsigned short us8;
typedef __attribute__((ext_vector_type(4))) unsigned short us4;
typedef __attribute__((ext_vector_type(2))) unsigned short us2;

#define DEVI static __device__ __forceinline__

DEVI unsigned short f2bf(float f){
  unsigned int u = __float_as_uint(f);
  u += 0x7fffu + ((u >> 16) & 1u);   // round-to-nearest-even
  return (unsigned short)(u >> 16);
}
DEVI float fexp2(float x){ float r; asm("v_exp_f32 %0, %1" : "=v"(r) : "v"(x)); return r; }
DEVI unsigned int cvt_pk_bf16(float lo, float hi){
  unsigned int r;
  asm("v_cvt_pk_bf16_f32 %0, %1, %2" : "=v"(r) : "v"(lo), "v"(hi));
  return r;
}
// XOR swizzle in ushort units: granule = 8 bf16 (16B). Row-major tile,
// row stride 64 / 256 ushorts. Bijective per row; consistent write+read.
DEVI int swz64(int r, int c){ return ((r << 6) + c) ^ ((r & 7) << 3); }
DEVI int swz256(int r, int c){ return ((r << 8) + c) ^ ((r & 7) << 3); }

// global->LDS DMA, 16B per lane. LDS dest = wave-uniform base + lane*16
// (linear); the swizzle lives in the per-lane GLOBAL source granule.
DEVI void gload16(const unsigned short* g, unsigned short* l){
  __builtin_amdgcn_global_load_lds(
      (const __attribute__((address_space(1))) unsigned int*)g,
      (__attribute__((address_space(3))) unsigned int*)l, 16, 0, 0);
}

// -- 0) prep_w (blocks 0..255) + gn_stats (blocks 256..383) in one launch --
__global__ __launch_bounds__(256) void prep_gn(
    const float* __restrict__ qkvw, const float* __restrict__ qkvb,
    const float* __restrict__ pw, unsigned short* __restrict__ wq,
    unsigned short* __restrict__ wp, float* __restrict__ bq,
    const float* __restrict__ x, const float* __restrict__ gw,
    const float* __restrict__ gb, float* __restrict__ ss){
  if (blockIdx.x < 256){
    const int i = blockIdx.x * 256 + threadIdx.x;     // i < 65536
    const float qs = 0.125f * 1.44269504f;            // hd^-0.5 * log2(e)
    if (i < 49152){                                   // qkv_w: 196608/4 float4s
      float4 v = ((const float4*)qkvw)[i];
      float sc = (i < 16384) ? qs : 1.f;              // q rows (o<256)
      us4 u; u[0]=f2bf(v.x*sc); u[1]=f2bf(v.y*sc); u[2]=f2bf(v.z*sc); u[3]=f2bf(v.w*sc);
      ((us4*)wq)[i] = u;
    }
    if (i < 16384){                                   // proj_w: 65536/4
      float4 v = ((const float4*)pw)[i];
      us4 u; u[0]=f2bf(v.x); u[1]=f2bf(v.y); u[2]=f2bf(v.z); u[3]=f2bf(v.w);
      ((us4*)wp)[i] = u;
    }
    if (i < 768) bq[i] = qkvb[i] * (i < 256 ? qs : 1.f);
    return;
  }
  const int gid = blockIdx.x - 256;                   // 0..127
  const int b = gid >> 5, g = gid & 31;
  const int t = threadIdx.x;
  const float4* base = (const float4*)(x + (((size_t)b * 256 + g * 8) << 12));
  float s = 0.f, q = 0.f;
  #pragma unroll
  for (int i = 0; i < 32; ++i){
    float4 v = base[i * 256 + t];
    s += v.x + v.y + v.z + v.w;
    q += v.x * v.x + v.y * v.y + v.z * v.z + v.w * v.w;
  }
  #pragma unroll
  for (int m = 32; m; m >>= 1){ s += __shfl_down(s, m); q += __shfl_down(q, m); }
  __shared__ float ps[4], pq[4];
  if ((t & 63) == 0){ ps[t >> 6] = s; pq[t >> 6] = q; }
  __syncthreads();
  if (t < 8){
    float S = ps[0] + ps[1] + ps[2] + ps[3];
    float Q = pq[0] + pq[1] + pq[2] + pq[3];
    float mean = S * (1.f / 32768.f);
    float var  = Q * (1.f / 32768.f) - mean * mean;
    float rstd = rsqrtf(var + 1e-5f);
    int c = g * 8 + t;
    float sc = gw[c] * rstd;
    ss[b * 256 + c] = sc;
    ss[1024 + b * 256 + c] = gb[c] - mean * sc;
  }
}

// ------- 2) normalize + transpose: xn_t[b][n][c] = bf16(x*scale+shift) -------
__global__ __launch_bounds__(256) void normalize_t(
    const float* __restrict__ x, const float* __restrict__ ss,
    unsigned short* __restrict__ xnt){
  const int n0 = blockIdx.x << 6, b = blockIdx.y;
  const int t = threadIdx.x;
  __shared__ unsigned short T[64 * 258];
  const float* xb = x + ((size_t)b << 20);
  const float* sc = ss + b * 256;
  const float* sh = ss + 1024 + b * 256;
  #pragma unroll 4
  for (int e = 0; e < 64; ++e){
    int idx = e * 256 + t;
    int c = idx >> 6, nl = idx & 63;
    float v = xb[((size_t)c << 12) + n0 + nl];
    T[nl * 258 + c] = f2bf(v * sc[c] + sh[c]);
  }
  __syncthreads();
  unsigned short* dst = xnt + ((((size_t)b << 12) + n0) << 8);
  #pragma unroll 4
  for (int e = 0; e < 32; ++e){
    int idx = e * 256 + t;
    int nl = idx >> 7, c2 = (idx & 127) << 1;
    *(us2*)(dst + (nl << 8) + c2) = *(const us2*)&T[nl * 258 + c2];
  }
}

// ---- 3) QKV GEMM: one block per (n0,h,b); B staged ONCE, loop which=q,k,v
//      with A restaged per-which (DMA overlapped with output stores).
__global__ __launch_bounds__(256) void qkv_gemm(
    const unsigned short* __restrict__ xnt, const unsigned short* __restrict__ W,
    const float* __restrict__ bias, unsigned short* __restrict__ qt,
    unsigned short* __restrict__ kt, unsigned short* __restrict__ vt){
  const int n0 = blockIdx.x << 6, h = blockIdx.y, b = blockIdx.z;
  const int t = threadIdx.x, l = t & 63, w = t >> 6;
  __shared__ __align__(16) unsigned short AB[32768];   // A: [0..16383], B: [16384..]
  unsigned short* Al = AB;
  unsigned short* Bl = AB + 16384;
  const unsigned short* Bsrc = xnt + ((((size_t)b << 12) + n0) << 8);
  // stage B once and A for which=0 (MT = h)
  #pragma unroll
  for (int e = 0; e < 8; ++e){
    const int idx = e * 256 + t;
    const int r = idx >> 5, g = idx & 31;
    const int gs = (g ^ (r & 7)) << 3;
    unsigned short* db = &AB[(e * 256 + (w << 6)) << 3];
    gload16(Bsrc + (r << 8) + gs, db + 16384);
    gload16(W + (size_t)(h << 6) * 256 + (r << 8) + gs, db);
  }
  __syncthreads();
  #pragma unroll
  for (int which = 0; which < 3; ++which){
    const int MT = (which << 2) + h;
    ffrag acc[4] = {{0,0,0,0},{0,0,0,0},{0,0,0,0},{0,0,0,0}};
    #pragma unroll
    for (int kc = 0; kc < 8; ++kc){
      bfrag a = *(const bfrag*)&Al[swz256((w << 4) + (l & 15), (kc << 5) + ((l >> 4) << 3))];
      #pragma unroll
      for (int fc = 0; fc < 4; ++fc){
        bfrag bb = *(const bfrag*)&Bl[swz256((fc << 4) + (l & 15), (kc << 5) + ((l >> 4) << 3))];
        acc[fc] = __builtin_amdgcn_mfma_f32_16x16x32_bf16(a, bb, acc[fc], 0, 0, 0);
      }
    }
    if (which < 2){
      __syncthreads();               // all waves done reading Al
      const unsigned short* Asrc = W + (size_t)((((which + 1) << 2) + h) << 6) * 256;
      #pragma unroll
      for (int e = 0; e < 8; ++e){
        const int idx = e * 256 + t;
        const int r = idx >> 5, g = idx & 31;
        const int gs = (g ^ (r & 7)) << 3;
        gload16(Asrc + (r << 8) + gs, &AB[(e * 256 + (w << 6)) << 3]);
      }
    }
    // output stores (overlap the A-DMA above)
    const int d0 = (w << 4) + ((l >> 4) << 2);
    float bi[4];
    #pragma unroll
    for (int r = 0; r < 4; ++r) bi[r] = bias[(MT << 6) + d0 + r];
    #pragma unroll
    for (int fc = 0; fc < 4; ++fc){
      int n = n0 + (fc << 4) + (l & 15);
      if (which < 2){               // q,k -> [b][h][n][d]
        unsigned short* dst = (which == 0 ? qt : kt) +
            (((size_t)(b * 4 + h)) << 18) + ((size_t)n << 6) + d0;
        us4 u;
        #pragma unroll
        for (int r = 0; r < 4; ++r) u[r] = f2bf(acc[fc][r] + bi[r]);
        *(us4*)dst = u;
      } else {                      // v -> [b][h][d][n], k-permuted cols
        const int np = n0 + ((fc & 2) << 4) + (((l >> 2) & 3) << 3)
                          + ((fc & 1) << 2) + (l & 3);
        #pragma unroll
        for (int r = 0; r < 4; ++r)
          vt[((((size_t)(b * 4 + h)) << 6) + d0 + r) * 4096 + np] = f2bf(acc[fc][r] + bi[r]);
      }
    }
    if (which < 2) __syncthreads(); // A landed (syncthreads drains vmcnt)
  }
}

// --- 4) flash attention, 8 waves / 512 thr, q-tile 128, in-block split-K ---
// r16-proven: serial body (setprio, rowsum-MFMA, no max-tracking), barrier
// every 2 iterations + per-wave counted vmcnt(2) mid-pair; 4-buffer K/V,
// depth-2 DMA, XCD-grouped decode.
__global__ __launch_bounds__(512, 4) void attn_kernel(
    const unsigned short* __restrict__ qt, const unsigned short* __restrict__ kt,
    const unsigned short* __restrict__ vt, unsigned short* __restrict__ at){
  const int id = blockIdx.x;                 // 0..511
  const int xc = id & 7, k2 = id >> 3;       // XCD c gets 2 bh
  const int bhid = (xc << 1) + (k2 >> 5);
  const int qx = k2 & 31;
  const int b = bhid >> 2, h = bhid & 3;
  const int q0 = qx << 7;
  const int t = threadIdx.x, l = t & 63, w = t >> 6;   // w in 0..7
  const int wq = w & 3, kh = w >> 2;
  const size_t bh = (size_t)bhid;
  // K bufs at ushort 0/4096/8192/12288 ; V bufs at 16384/20480/24576/28672.
  // Q staged in kbuf2 (rows 0-63) + kbuf3 (rows 64-127), consumed pre-loop.
  __shared__ __align__(16) unsigned short S[32768];    // 64 KB
  const unsigned short* kbase = kt + (bh << 18);
  const unsigned short* vbase = vt + (bh << 18);

  const int row = t >> 3;                        // 0..63
  const int gx = ((t & 7) ^ (row & 7)) << 3;     // swizzled source granule col
  const int koff = (row << 6) + gx;
  unsigned short* ldst = &S[w << 9];             // wave-uniform dest base
  // prologue issues: Q0->kbuf2, Q1->kbuf3, K0->kbuf0, V0->vbuf0, K1, V1
  const unsigned short* qsrc = qt + (bh << 18) + ((size_t)q0 << 6);
  gload16(qsrc + koff, ldst + 8192);
  gload16(qsrc + 4096 + koff, ldst + 12288);
  gload16(kbase + koff, ldst);
  gload16(vbase + (row << 12) + gx, ldst + 16384);
  gload16(kbase + 4096 + koff, ldst + 4096);
  gload16(vbase + (row << 12) + 64 + gx, ldst + 20480);
  asm volatile("s_waitcnt vmcnt(4)" ::: "memory");  // Q landed
  __builtin_amdgcn_s_barrier();
  __builtin_amdgcn_sched_barrier(0);
  const int qreg = (wq >> 1) ? 12288 : 8192;
  const int qrow = ((wq & 1) << 5) + (l & 15);
  bfrag bq00 = *(const bfrag*)&S[qreg + swz64(qrow,      (l >> 4) << 3)];
  bfrag bq01 = *(const bfrag*)&S[qreg + swz64(qrow, 32 + ((l >> 4) << 3))];
  bfrag bq10 = *(const bfrag*)&S[qreg + swz64(qrow + 16,      (l >> 4) << 3)];
  bfrag bq11 = *(const bfrag*)&S[qreg + swz64(qrow + 16, 32 + ((l >> 4) << 3))];
  asm volatile("s_waitcnt lgkmcnt(0)" ::: "memory");
  asm volatile("s_waitcnt vmcnt(2)" ::: "memory");  // K0,V0 landed; K1,V1 fly
  __builtin_amdgcn_s_barrier();      // Q consumed; kbuf2/3 writable
  __builtin_amdgcn_sched_barrier(0);

  ffrag acc[2][4] = {{{0,0,0,0},{0,0,0,0},{0,0,0,0},{0,0,0,0}},
                     {{0,0,0,0},{0,0,0,0},{0,0,0,0},{0,0,0,0}}};
  ffrag zs[2] = {{0,0,0,0},{0,0,0,0}};     // rowsum accumulators (row-indexed)
  const ffrag zf = {0.f, 0.f, 0.f, 0.f};
  bfrag onesB;
  #pragma unroll
  for (int j = 0; j < 8; ++j) onesB[j] = (short)0x3F80;   // bf16 1.0

  auto body = [&](int kbr, int vbr) __attribute__((always_inline)) {
    ffrag s[2][2];
    __builtin_amdgcn_s_setprio(1);
    #pragma unroll
    for (int j = 0; j < 2; ++j){
      const int fc = (kh << 1) + j;
      bfrag ak0 = *(const bfrag*)&S[kbr + swz64((fc << 4) + (l & 15), (l >> 4) << 3)];
      bfrag ak1 = *(const bfrag*)&S[kbr + swz64((fc << 4) + (l & 15), 32 + ((l >> 4) << 3))];
      ffrag z0 = __builtin_amdgcn_mfma_f32_16x16x32_bf16(ak0, bq00, zf, 0, 0, 0);
      z0 = __builtin_amdgcn_mfma_f32_16x16x32_bf16(ak1, bq01, z0, 0, 0, 0);
      ffrag z1 = __builtin_amdgcn_mfma_f32_16x16x32_bf16(ak0, bq10, zf, 0, 0, 0);
      z1 = __builtin_amdgcn_mfma_f32_16x16x32_bf16(ak1, bq11, z1, 0, 0, 0);
      s[0][j] = z0; s[1][j] = z1;
    }
    __builtin_amdgcn_s_setprio(0);
    float p[2][2][4];
    #pragma unroll
    for (int g = 0; g < 2; ++g){
      #pragma unroll
      for (int j = 0; j < 2; ++j){
        #pragma unroll
        for (int r = 0; r < 4; ++r) p[g][j][r] = fexp2(s[g][j][r]);
      }
    }
    union { bfrag bb; unsigned int u[4]; } A0, A1;
    A0.u[0] = cvt_pk_bf16(p[0][0][0], p[0][0][1]); A0.u[1] = cvt_pk_bf16(p[0][0][2], p[0][0][3]);
    A0.u[2] = cvt_pk_bf16(p[0][1][0], p[0][1][1]); A0.u[3] = cvt_pk_bf16(p[0][1][2], p[0][1][3]);
    A1.u[0] = cvt_pk_bf16(p[1][0][0], p[1][0][1]); A1.u[1] = cvt_pk_bf16(p[1][0][2], p[1][0][3]);
    A1.u[2] = cvt_pk_bf16(p[1][1][0], p[1][1][1]); A1.u[3] = cvt_pk_bf16(p[1][1][2], p[1][1][3]);
    __builtin_amdgcn_s_setprio(1);
    zs[0] = __builtin_amdgcn_mfma_f32_16x16x32_bf16(A0.bb, onesB, zs[0], 0, 0, 0);
    zs[1] = __builtin_amdgcn_mfma_f32_16x16x32_bf16(A1.bb, onesB, zs[1], 0, 0, 0);
    #pragma unroll
    for (int fc = 0; fc < 4; ++fc){
      bfrag vv = *(const bfrag*)&S[vbr + swz64((fc << 4) + (l & 15),
                                              (kh << 5) + ((l >> 4) << 3))];
      acc[0][fc] = __builtin_amdgcn_mfma_f32_16x16x32_bf16(A0.bb, vv, acc[0][fc], 0, 0, 0);
      acc[1][fc] = __builtin_amdgcn_mfma_f32_16x16x32_bf16(A1.bb, vv, acc[1][fc], 0, 0, 0);
    }
    __builtin_amdgcn_s_setprio(0);
  };
  auto issue2 = [&](int kti2, int buf) __attribute__((always_inline)) {
    gload16(kbase + (kti2 << 12) + koff, ldst + (buf << 12));
    gload16(vbase + (row << 12) + (kti2 << 6) + gx, ldst + 16384 + (buf << 12));
  };

#define ATTN_PAIR(KE, BE, BO)                                 \
    issue2((KE) + 2, ((BE) + 2) & 3);                         \
    body((BE) << 12, 16384 + ((BE) << 12));                   \
    asm volatile("s_waitcnt vmcnt(2)" ::: "memory");          \
    __builtin_amdgcn_sched_barrier(0);                        \
    issue2((KE) + 3, ((BO) + 2) & 3);                         \
    body((BO) << 12, 16384 + ((BO) << 12));                   \
    asm volatile("s_waitcnt vmcnt(2)" ::: "memory");          \
    __builtin_amdgcn_s_barrier();                             \
    __builtin_amdgcn_sched_barrier(0);

  for (int base = 0; base < 60; base += 4){
    ATTN_PAIR(base + 0, 0, 1)
    ATTN_PAIR(base + 2, 2, 3)
  }
  ATTN_PAIR(60, 0, 1)          // issues tiles 62->buf2, 63->buf3
  // tail pair (62,63): no issues
  body(2 << 12, 16384 + (2 << 12));
  asm volatile("s_waitcnt vmcnt(0)" ::: "memory");
  __builtin_amdgcn_sched_barrier(0);
  body(3 << 12, 16384 + (3 << 12));
#undef ATTN_PAIR

  __syncthreads();                 // retire all tile reads; LDS free
  float* Sf = (float*)S;
  // phase 1: kh=1 publishes its rowsums (row-indexed) at Sf[8192..]
  if (kh == 1 && (l & 15) == 0){
    #pragma unroll
    for (int g = 0; g < 2; ++g){
      #pragma unroll
      for (int r = 0; r < 4; ++r)
        Sf[8192 + (wq << 5) + (g << 4) + ((l >> 4) << 2) + r] = zs[g][r];
    }
  }
  __syncthreads();
  float inv[2][4];
  if (kh == 0){
    #pragma unroll
    for (int g = 0; g < 2; ++g){
      #pragma unroll
      for (int r = 0; r < 4; ++r)
        inv[g][r] = 1.f / (zs[g][r] +
            Sf[8192 + (wq << 5) + (g << 4) + ((l >> 4) << 2) + r]);
    }
  }
  __syncthreads();
  // phase 2: kh=1 publishes acc f32 (128q x 64d = 32 KB at Sf[0..8191])
  if (kh == 1){
    #pragma unroll
    for (int g = 0; g < 2; ++g){
      #pragma unroll
      for (int fc = 0; fc < 4; ++fc){
        #pragma unroll
        for (int r = 0; r < 4; ++r)
          Sf[((wq << 5) + (g << 4) + ((l >> 4) << 2) + r) * 64 + (fc << 4) + (l & 15)] =
              acc[g][fc][r];
      }
    }
  }
  __syncthreads();
  if (kh == 0){
    #pragma unroll
    for (int g = 0; g < 2; ++g){
      #pragma unroll
      for (int fc = 0; fc < 4; ++fc){
        #pragma unroll
        for (int r = 0; r < 4; ++r){
          const int ql = (wq << 5) + (g << 4) + ((l >> 4) << 2) + r;
          float ob = Sf[ql * 64 + (fc << 4) + (l & 15)];
          float v = (acc[g][fc][r] + ob) * inv[g][r];
          at[((((size_t)b << 12) + q0 + ql) << 8) + (h << 6) + (fc << 4) + (l & 15)] =
              f2bf(v);
        }
      }
    }
  }
}

// -------- 5) proj GEMM + bias + residual: out = x + W@attn_out + b --------
__global__ __launch_bounds__(256) void proj_gemm(
    const unsigned short* __restrict__ at, const unsigned short* __restrict__ W,
    const float* __restrict__ bias, const float* __restrict__ x,
    float* __restrict__ out){
  const int n0 = blockIdx.x << 6, MT = blockIdx.y, b = blockIdx.z;
  const int t = threadIdx.x, l = t & 63, w = t >> 6;
  __shared__ __align__(16) unsigned short AB[32768];   // A: [0..16383], B: [16384..]
  unsigned short* Al = AB;
  unsigned short* Bl = AB + 16384;
  const unsigned short* Asrc = W + (size_t)(MT << 6) * 256;
  const unsigned short* Bsrc = at + ((((size_t)b << 12) + n0) << 8);
  #pragma unroll
  for (int e = 0; e < 8; ++e){
    const int idx = e * 256 + t;
    const int r = idx >> 5, g = idx & 31;
    const int gs = (g ^ (r & 7)) << 3;
    unsigned short* db = &AB[(e * 256 + (w << 6)) << 3];
    gload16(Asrc + (r << 8) + gs, db);
    gload16(Bsrc + (r << 8) + gs, db + 16384);
  }
  __syncthreads();
  ffrag acc[4] = {{0,0,0,0},{0,0,0,0},{0,0,0,0},{0,0,0,0}};
  #pragma unroll
  for (int kc = 0; kc < 8; ++kc){
    bfrag a = *(const bfrag*)&Al[swz256((w << 4) + (l & 15), (kc << 5) + ((l >> 4) << 3))];
    #pragma unroll
    for (int fc = 0; fc < 4; ++fc){
      bfrag bb = *(const bfrag*)&Bl[swz256((fc << 4) + (l & 15), (kc << 5) + ((l >> 4) << 3))];
      acc[fc] = __builtin_amdgcn_mfma_f32_16x16x32_bf16(a, bb, acc[fc], 0, 0, 0);
    }
  }
  const int co = (MT << 6) + (w << 4) + ((l >> 4) << 2);
  #pragma unroll
  for (int fc = 0; fc < 4; ++fc){
    int n = n0 + (fc << 4) + (l & 15);
    #pragma unroll
    for (int r = 0; r < 4; ++r){
      size_t o = (((size_t)b * 256 + co + r) << 12) + n;
      out[o] = acc[fc][r] + bias[co + r] + x[o];
    }
  }
}

extern "C" void kernel_launch(void* const* d_in, const int* in_sizes, int n_in,
                              void* d_out, int out_size, void* d_ws, size_t ws_size,
                              hipStream_t stream){
  const float* x    = (const float*)d_in[0];
  const float* gw   = (const float*)d_in[1];
  const float* gb   = (const float*)d_in[2];
  const float* qkvw = (const float*)d_in[3];
  const float* qkvb = (const float*)d_in[4];
  const float* pw   = (const float*)d_in[5];
  const float* pb   = (const float*)d_in[6];
  float* out = (float*)d_out;

  float* ss = (float*)d_ws;
  unsigned short* xnt = (unsigned short*)((char*)d_ws + 16384);
  unsigned short* qt  = xnt + (size_t)4 * 4096 * 256;
  unsigned short* kt  = qt  + (size_t)16 * 4096 * 64;
  unsigned short* vt  = kt  + (size_t)16 * 4096 * 64;
  unsigned short* at  = vt  + (size_t)16 * 4096 * 64;
  unsigned short* wq  = at  + (size_t)4 * 4096 * 256;
  unsigned short* wp  = wq  + (size_t)768 * 256;
  float*          bq  = (float*)(wp + (size_t)256 * 256);

  prep_gn    <<<384, 256, 0, stream>>>(qkvw, qkvb, pw, wq, wp, bq, x, gw, gb, ss);
  normalize_t<<<dim3(64, 4), 256, 0, stream>>>(x, ss, xnt);
  qkv_gemm   <<<dim3(64, 4, 4), 256, 0, stream>>>(xnt, wq, bq, qt, kt, vt);
  attn_kernel<<<dim3(512), 512, 0, stream>>>(qt, kt, vt, at);
  proj_gemm  <<<dim3(64, 4, 4), 256, 0, stream>>>(at, wp, pb, x, out);
}